// Round 18
// baseline (13.815 us; speedup 1.0000x reference)
//
#include <hip/hip_runtime.h>
#include <math.h>

// RecurrentNALU single step. B=4096, IN=128, HID=128, CAT=256.
// R18: two-kernel. Prepass converts x=concat(x_t,h_tm1) and Wa/Ga/Wm to bf16
// into d_ws, laid out as each block's exact swizzled LDS image (64-row x-panels;
// 32-col weight groups). Main kernel stages via global_load_lds_dwordx4 (pure
// DMA: pre-swizzled global source + linear LDS dest, guide §5), one barrier,
// then the R16/R17 loop: 8 K-steps x (4 ds_read_b128 + 4 MFMA), m=exp(s1-c1)
// first-order log-series, c1 via ones-fragment MFMA. Fallback to the R17
// single kernel if ws_size < 2.3 MB.

#define HID    128
#define CAT    256
#define ROWS_B 64
#define COLS_B 32
#define GRID   ((4096 / ROWS_B) * (HID / COLS_B))  // 256

#define XBYTES   (ROWS_B * CAT * 2)            // 32768 per x panel
#define WGBYTES  (3 * COLS_B * CAT * 2)        // 49152 per col-group
#define WS_WOFF  (64 * XBYTES)                 // 2097152
#define WS_NEED  (WS_WOFF + 4 * WGBYTES)       // 2293760

typedef float  f32x4  __attribute__((ext_vector_type(4)));
typedef short  bf16x8 __attribute__((ext_vector_type(8)));

static __device__ __forceinline__ unsigned int cvtpk(float lo, float hi) {
    unsigned int r;
    asm("v_cvt_pk_bf16_f32 %0, %1, %2" : "=v"(r) : "v"(lo), "v"(hi));
    return r;
}
static __device__ __forceinline__ uint4 pack8(const float* p) {
    const float4 v0 = *reinterpret_cast<const float4*>(p);
    const float4 v1 = *reinterpret_cast<const float4*>(p + 4);
    uint4 pk;
    pk.x = cvtpk(v0.x, v0.y); pk.y = cvtpk(v0.z, v0.w);
    pk.z = cvtpk(v1.x, v1.y); pk.w = cvtpk(v1.z, v1.w);
    return pk;
}

// ---------- prepass: fp32 -> bf16 swizzled images in d_ws ----------
__global__ __launch_bounds__(256)
void prepack_kernel(const float* __restrict__ x_t,
                    const float* __restrict__ h_tm1,
                    const float* __restrict__ Wa_,
                    const float* __restrict__ Ga_,
                    const float* __restrict__ Wm_,
                    unsigned char* __restrict__ wsb)
{
    const int i = blockIdx.x * 256 + threadIdx.x;
    if (i < 131072) {                       // x: 64 panels x 64 rows x 32 octets
        const int p  = i >> 11;
        const int sr = (i >> 5) & 63;
        const int oc = i & 31;
        const int row = p * 64 + sr;
        const int c = oc * 8;
        const float* src = (c < 128)
            ? x_t   + (size_t)row * 128 + c
            : h_tm1 + (size_t)row * 128 + (c - 128);
        const uint4 pk = pack8(src);
        const int slot = oc ^ (sr & 7);
        *reinterpret_cast<uint4*>(wsb + (size_t)p * XBYTES + sr * 512 + slot * 16) = pk;
    } else if (i < 131072 + 12288) {        // w: 4 groups x 3 arrays x 32 cols x 32 octets
        const int j  = i - 131072;
        const int cg = j / 3072;
        const int r0 = j - cg * 3072;
        const int a  = r0 >> 10;
        const int rr = r0 & 1023;
        const int wc = rr >> 5;
        const int oc = rr & 31;
        const float* const srcs[3] = {Wa_, Ga_, Wm_};
        const float* src = srcs[a] + (size_t)(cg * 32 + wc) * CAT + oc * 8;
        const uint4 pk = pack8(src);
        const int slot = oc ^ (wc & 7);
        *reinterpret_cast<uint4*>(wsb + WS_WOFF + (size_t)cg * WGBYTES
                                  + a * 16384 + wc * 512 + slot * 16) = pk;
    }
}

// ---------- main kernel: DMA staging + MFMA loop ----------
__global__ __launch_bounds__(512, 2)
void nalu_main_kernel(const unsigned char* __restrict__ wsb,
                      float* __restrict__ out)
{
    // one linear LDS image: x panel (32768 B) then weights (49152 B) = 80 KB
    __shared__ unsigned short lds[40960];

    const int bid = blockIdx.x;
    const int wg  = (bid & 7) * (GRID >> 3) + (bid >> 3);  // XCD-bijective
    const int p   = wg >> 2;        // x panel 0..63
    const int cg  = wg & 3;         // col group 0..3

    const int tid  = threadIdx.x;
    const int lane = tid & 63;
    const int wid  = __builtin_amdgcn_readfirstlane(tid >> 6); // 0..7

    // ---- staging: 10 global_load_lds_dwordx4 per thread, no VALU ----
    {
        const unsigned char* xsrc = wsb + (size_t)p * XBYTES;
        const unsigned char* wsrc = wsb + WS_WOFF + (size_t)cg * WGBYTES;
        unsigned char* lbase = reinterpret_cast<unsigned char*>(&lds[0]);
        const int wo = wid * 1024;
        #pragma unroll
        for (int r = 0; r < 4; ++r) {      // x: 4 x 8192 B rounds
            __builtin_amdgcn_global_load_lds(
                (const __attribute__((address_space(1))) void*)(xsrc + r * 8192 + wo + lane * 16),
                (__attribute__((address_space(3))) void*)(lbase + r * 8192 + wo),
                16, 0, 0);
        }
        #pragma unroll
        for (int r = 0; r < 6; ++r) {      // w: 6 x 8192 B rounds
            __builtin_amdgcn_global_load_lds(
                (const __attribute__((address_space(1))) void*)(wsrc + r * 8192 + wo + lane * 16),
                (__attribute__((address_space(3))) void*)(lbase + 32768 + r * 8192 + wo),
                16, 0, 0);
        }
    }
    __syncthreads();   // drains vmcnt; the ONLY barrier

    const int rowT = (wid >> 1) << 4;     // row tile 0..3
    const int chf  = wid & 1;             // col half
    const int n    = lane & 15;           // C col within half
    const int kg   = lane >> 4;           // k-group / C row-group
    const int ncol = (chf << 4) + n;      // weight col; (ncol&7) == (n&7)

    const short one_bf = (short)0x3F80;   // bf16 1.0
    const bf16x8 fones = {one_bf, one_bf, one_bf, one_bf,
                          one_bf, one_bf, one_bf, one_bf};

    f32x4 aa = {0.f, 0.f, 0.f, 0.f};
    f32x4 gg = {0.f, 0.f, 0.f, 0.f};
    f32x4 t1 = {0.f, 0.f, 0.f, 0.f};
    f32x4 cc = {0.f, 0.f, 0.f, 0.f};

    // lds element maps: x(row,e) = lds[row*256 + e];
    // w(a,wc,e) = lds[16384 + a*8192 + wc*256 + e]
    #pragma unroll 4
    for (int i = 0; i < 8; ++i) {
        const int ko = i * 4;
        const int fo = ((ko + kg) ^ (n & 7)) << 3;
        const unsigned short* xr = &lds[(rowT + n) * 256 + fo];
        const unsigned short* wr = &lds[16384 + ncol * 256 + fo];
        const bf16x8 fa  = *reinterpret_cast<const bf16x8*>(xr);
        const bf16x8 fwa = *reinterpret_cast<const bf16x8*>(wr);
        const bf16x8 fga = *reinterpret_cast<const bf16x8*>(wr + 8192);
        const bf16x8 fwm = *reinterpret_cast<const bf16x8*>(wr + 16384);
        aa = __builtin_amdgcn_mfma_f32_16x16x32_bf16(fa,    fwa, aa, 0, 0, 0);
        gg = __builtin_amdgcn_mfma_f32_16x16x32_bf16(fa,    fga, gg, 0, 0, 0);
        t1 = __builtin_amdgcn_mfma_f32_16x16x32_bf16(fa,    fwm, t1, 0, 0, 0);
        cc = __builtin_amdgcn_mfma_f32_16x16x32_bf16(fones, fwm, cc, 0, 0, 0);
    }

    // ---- epilogue ----
    const int grow = (p * 64) + rowT + (kg << 2);
    const int gcol = (cg * 32) + (chf << 4) + n;
    #pragma unroll
    for (int rr = 0; rr < 4; ++rr) {
        const float m  = __expf(t1[rr] - cc[rr]);
        const float gv = 1.f / (1.f + __expf(-gg[rr]));
        out[(size_t)(grow + rr) * HID + gcol] = fmaf(gv, aa[rr] - m, m);
    }
}

// ---------- fallback: R17 single kernel (ws too small) ----------
__global__ __launch_bounds__(512, 2)
void nalu_step_kernel(const float* __restrict__ x_t,
                      const float* __restrict__ h_tm1,
                      const float* __restrict__ Wa_,
                      const float* __restrict__ Wm_,
                      const float* __restrict__ Ga_,
                      float* __restrict__ out)
{
    __shared__ unsigned short xs[ROWS_B][CAT];
    __shared__ unsigned short ws[3][COLS_B][CAT];

    const int bid = blockIdx.x;
    const int wg  = (bid & 7) * (GRID >> 3) + (bid >> 3);
    const int rowBase = (wg >> 2) * ROWS_B;
    const int colBase = (wg & 3) * COLS_B;

    const int tid = threadIdx.x;
    {
        const int sr = tid >> 3;
        const int sq = tid & 7;
        const float* sb = (sq < 4)
            ? x_t   + (size_t)(rowBase + sr) * 128 + sq * 32
            : h_tm1 + (size_t)(rowBase + sr) * 128 + (sq - 4) * 32;
        #pragma unroll
        for (int j = 0; j < 4; ++j) {
            const uint4 pk = pack8(sb + j * 8);
            const int o = sq * 4 + j;
            *reinterpret_cast<uint4*>(&xs[sr][(o ^ (sr & 7)) << 3]) = pk;
        }
    }
    {
        const int wc = tid >> 4;
        const int s0 = (tid & 15) * 2;
        const float* const srcs[3] = {Wa_, Ga_, Wm_};
        #pragma unroll
        for (int a = 0; a < 3; ++a)
            #pragma unroll
            for (int s = 0; s < 2; ++s) {
                const int sg = s0 + s;
                const uint4 pk = pack8(srcs[a] + (size_t)(colBase + wc) * CAT + sg * 8);
                *reinterpret_cast<uint4*>(&ws[a][wc][(sg ^ (wc & 7)) << 3]) = pk;
            }
    }
    __syncthreads();

    const int lane = tid & 63;
    const int wid  = __builtin_amdgcn_readfirstlane(tid >> 6);
    const int rowT = (wid >> 1) << 4;
    const int chf  = wid & 1;
    const int n    = lane & 15;
    const int kg   = lane >> 4;
    const int ncol = (chf << 4) + n;

    const short one_bf = (short)0x3F80;
    const bf16x8 fones = {one_bf, one_bf, one_bf, one_bf,
                          one_bf, one_bf, one_bf, one_bf};
    f32x4 aa = {0.f, 0.f, 0.f, 0.f};
    f32x4 gg = {0.f, 0.f, 0.f, 0.f};
    f32x4 t1 = {0.f, 0.f, 0.f, 0.f};
    f32x4 cc = {0.f, 0.f, 0.f, 0.f};

    #pragma unroll 4
    for (int i = 0; i < 8; ++i) {
        const int ko = i * 4;
        const int fo = ((ko + kg) ^ (n & 7)) << 3;
        const bf16x8 fa  = *reinterpret_cast<const bf16x8*>(&xs[rowT + n][fo]);
        const bf16x8 fwa = *reinterpret_cast<const bf16x8*>(&ws[0][ncol][fo]);
        const bf16x8 fga = *reinterpret_cast<const bf16x8*>(&ws[1][ncol][fo]);
        const bf16x8 fwm = *reinterpret_cast<const bf16x8*>(&ws[2][ncol][fo]);
        aa = __builtin_amdgcn_mfma_f32_16x16x32_bf16(fa,    fwa, aa, 0, 0, 0);
        gg = __builtin_amdgcn_mfma_f32_16x16x32_bf16(fa,    fga, gg, 0, 0, 0);
        t1 = __builtin_amdgcn_mfma_f32_16x16x32_bf16(fa,    fwm, t1, 0, 0, 0);
        cc = __builtin_amdgcn_mfma_f32_16x16x32_bf16(fones, fwm, cc, 0, 0, 0);
    }

    const int grow = rowBase + rowT + (kg << 2);
    const int gcol = colBase + (chf << 4) + n;
    #pragma unroll
    for (int rr = 0; rr < 4; ++rr) {
        const float m  = __expf(t1[rr] - cc[rr]);
        const float gv = 1.f / (1.f + __expf(-gg[rr]));
        out[(size_t)(grow + rr) * HID + gcol] = fmaf(gv, aa[rr] - m, m);
    }
}

extern "C" void kernel_launch(void* const* d_in, const int* in_sizes, int n_in,
                              void* d_out, int out_size, void* d_ws, size_t ws_size,
                              hipStream_t stream)
{
    const float* x_t   = (const float*)d_in[0];
    const float* h_tm1 = (const float*)d_in[1];
    const float* W_add = (const float*)d_in[2];
    const float* W_mul = (const float*)d_in[3];
    const float* G_add = (const float*)d_in[4];
    float* out = (float*)d_out;

    if (ws_size >= WS_NEED && d_ws) {
        unsigned char* wsb = (unsigned char*)d_ws;
        prepack_kernel<<<(131072 + 12288 + 255) / 256, 256, 0, stream>>>(
            x_t, h_tm1, W_add, G_add, W_mul, wsb);
        nalu_main_kernel<<<GRID, 512, 0, stream>>>(wsb, out);
    } else {
        nalu_step_kernel<<<GRID, 512, 0, stream>>>(
            x_t, h_tm1, W_add, W_mul, G_add, out);
    }
}